// Round 18
// baseline (263.869 us; speedup 1.0000x reference)
//
#include <hip/hip_runtime.h>
#include <hip/hip_bf16.h>
#include <math.h>

#define D 512
#define BB 4
#define TT 4096
#define KT 32

typedef __attribute__((ext_vector_type(8))) short short8v;
typedef __attribute__((ext_vector_type(4))) short short4v;
typedef __attribute__((ext_vector_type(4))) float float4v;

__device__ inline short f2bf(float x) {
    __hip_bfloat16 h = __float2bfloat16(x);
    return *reinterpret_cast<short*>(&h);
}
__device__ inline float bf2f(short s) {
    __hip_bfloat16 h = *reinterpret_cast<__hip_bfloat16*>(&s);
    return __bfloat162float(h);
}

// ============ Fused QKV projection + V-transpose ============
// q,k row-major bf16; v written directly into sigma-permuted transposed vt layout
// via an LDS round-trip (R17-verified).
__global__ __launch_bounds__(256) void gemm_qkv(
    const float* __restrict__ x,
    const float* __restrict__ Wq, const float* __restrict__ Wk, const float* __restrict__ Wv,
    __hip_bfloat16* __restrict__ q, __hip_bfloat16* __restrict__ k, __hip_bfloat16* __restrict__ vt)
{
    __shared__ short As[64][72];       // +8 bf16 pad -> conflict-floor b128 reads
    __shared__ short Bs[3][64][72];
    __shared__ short Ts[64][66];       // V-tile transpose buffer [d_local][t_local]
    const int tid = threadIdx.x;
    const int m0 = blockIdx.x * 64, n0 = blockIdx.y * 64;
    const int w = tid >> 6, lane = tid & 63, lm = lane & 15, g = lane >> 4;

    float4v acc[3][4];
    #pragma unroll
    for (int z = 0; z < 3; ++z)
        #pragma unroll
        for (int i = 0; i < 4; ++i) acc[z][i] = (float4v){0.f,0.f,0.f,0.f};

    for (int k0 = 0; k0 < 512; k0 += 64) {
        __syncthreads();
        #pragma unroll
        for (int u = 0; u < 4; ++u) {          // stage A (x), convert f32->bf16, ONCE
            int ch = tid + 256*u;
            int r = ch >> 4, c = (ch & 15) * 4;
            float4 xv = *reinterpret_cast<const float4*>(x + (size_t)(m0 + r)*512 + k0 + c);
            short4v sv = { f2bf(xv.x), f2bf(xv.y), f2bf(xv.z), f2bf(xv.w) };
            *reinterpret_cast<short4v*>(&As[r][c]) = sv;
        }
        #pragma unroll
        for (int z = 0; z < 3; ++z) {          // stage B for all 3 weight matrices
            const float* W = (z == 0) ? Wq : (z == 1) ? Wk : Wv;
            #pragma unroll
            for (int u = 0; u < 4; ++u) {
                int ch = tid + 256*u;
                int r = ch >> 4, c = (ch & 15) * 4;
                float4 wv = *reinterpret_cast<const float4*>(W + (size_t)(n0 + r)*512 + k0 + c);
                short4v sv = { f2bf(wv.x), f2bf(wv.y), f2bf(wv.z), f2bf(wv.w) };
                *reinterpret_cast<short4v*>(&Bs[z][r][c]) = sv;
            }
        }
        __syncthreads();
        #pragma unroll
        for (int ks = 0; ks < 2; ++ks) {
            short8v a = *reinterpret_cast<const short8v*>(&As[16*w + lm][ks*32 + 8*g]);
            #pragma unroll
            for (int z = 0; z < 3; ++z)
                #pragma unroll
                for (int nt = 0; nt < 4; ++nt) {
                    short8v bv = *reinterpret_cast<const short8v*>(&Bs[z][16*nt + lm][ks*32 + 8*g]);
                    acc[z][nt] = __builtin_amdgcn_mfma_f32_16x16x32_bf16(a, bv, acc[z][nt], 0, 0, 0);
                }
        }
    }

    // q, k: direct row-major writes (D layout: row = 4*(lane>>4)+reg, col = lane&15)
    #pragma unroll
    for (int z = 0; z < 2; ++z) {
        __hip_bfloat16* C = (z == 0) ? q : k;
        const float alpha = (z == 0) ? 0.044194173824159216f : 1.f;   // fold 1/sqrt(512) into q
        #pragma unroll
        for (int nt = 0; nt < 4; ++nt)
            #pragma unroll
            for (int r = 0; r < 4; ++r) {
                int row = m0 + 16*w + 4*g + r;
                int col = n0 + 16*nt + lm;
                C[(size_t)row*512 + col] = __float2bfloat16(acc[z][nt][r] * alpha);
            }
    }

    // v: transposed store into Ts[d_local][t_local] (bf16), then sigma-permuted coalesced write
    #pragma unroll
    for (int nt = 0; nt < 4; ++nt)
        #pragma unroll
        for (int r = 0; r < 4; ++r)
            Ts[16*nt + lm][16*w + 4*g + r] = f2bf(acc[2][nt][r]);
    __syncthreads();

    {
        const int dloc = tid >> 2;             // 0..63
        const int qs   = tid & 3;              // 16-t chunk
        const int bb   = m0 >> 12;             // batch (TT=4096; 64-row tiles never straddle)
        const int tb   = m0 & (TT - 1);
        short tmp[16];
        #pragma unroll
        for (int i = 0; i < 16; ++i) {
            int tp = qs*16 + i;
            int blk = tp & 32;
            int p = tp & 31;
            int tloc = blk + 16*((p & 7) >> 2) + 4*(p >> 3) + (p & 3);   // inverse sigma perm
            tmp[i] = Ts[dloc][tloc];
        }
        short* dst = (short*)vt + (size_t)bb*D*TT + (size_t)(n0 + dloc)*TT + tb + qs*16;
        *reinterpret_cast<short8v*>(dst)     = *reinterpret_cast<short8v*>(&tmp[0]);
        *reinterpret_cast<short8v*>(dst + 8) = *reinterpret_cast<short8v*>(&tmp[8]);
    }
}

// ============ Flash attention, QB=128, 4-way split-K + triangle pairing (R15/R16-verified) ============
__global__ __launch_bounds__(512, 1) void attn_split(
    const __hip_bfloat16* __restrict__ qg, const __hip_bfloat16* __restrict__ kg,
    const __hip_bfloat16* __restrict__ vtg,
    __hip_bfloat16* __restrict__ U0, __hip_bfloat16* __restrict__ U1,
    __hip_bfloat16* __restrict__ U2, __hip_bfloat16* __restrict__ U3,
    float* __restrict__ mArr, float* __restrict__ lArr)
{
    __shared__ short Ks[2][KT][512];           // 64KB; row r chunk c holds K chunk c^(4*(r&15))
    __shared__ short Vs[2][512][32];           // 64KB; row d chunk c holds vt chunk c^((d>>1)&3)

    const int tid = threadIdx.x;
    const int w = tid >> 6, lane = tid & 63, lm = lane & 15, g = lane >> 4;
    const int qgp = w;                         // q-group 0..7 (full-d wave)
    const int idx = blockIdx.x;
    const int b  = idx & 3;                    // batch -> XCD spread
    const int u  = idx >> 2;
    const int pr = u >> 2;                     // pair index 0..15
    const int s  = u & 3;                      // key-quarter

    const short* qp = (const short*)qg  + (size_t)b*TT*D;
    const short* kp = (const short*)kg  + (size_t)b*TT*D;
    const short* vp = (const short*)vtg + (size_t)b*D*TT;

    short* Uo = (short*)((s == 0) ? U0 : (s == 1) ? U1 : (s == 2) ? U2 : U3);
    float* mo = mArr + (size_t)s * BB * TT;
    float* lo = lArr + (size_t)s * BB * TT;

    const int vswz = (lane & 3) ^ ((lane >> 3) & 3);   // V stage: source chunk for this lane

    // per-lane LDS base pointers (element = short)
    const short* k0p = &Ks[0][lm][g*8];        // QK read: kc + 32*(ss^lm); second subtile +8192
    const short* k1p = &Ks[1][lm][g*8];
    const int vcid = g ^ ((lm >> 1) & 3);
    const short* v0p = &Vs[0][lm][vcid*8];     // PV read: vc + dt*512 (literal), dt 0..31
    const short* v1p = &Vs[1][lm][vcid*8];

    // stage k-tile T (global index) into buffer BUF; 8 waves split the 64 DMA instrs
    #define STAGE_KV(T, BUF) do {                                                  \
        const short* kt_ = kp + (size_t)(T) * KT * D;                              \
        const int ksv_ = (T) * KT;                                                 \
        _Pragma("unroll")                                                          \
        for (int i_ = 0; i_ < 4; ++i_) {                                           \
            int r_ = 4*w + i_;                                                     \
            int c_ = (lane ^ ((r_ & 15) << 2)) & 63;                               \
            __builtin_amdgcn_global_load_lds(                                      \
                (const __attribute__((address_space(1))) void*)(kt_ + (size_t)r_*D + c_*8), \
                (__attribute__((address_space(3))) void*)(&Ks[BUF][r_][0]),        \
                16, 0, 0);                                                         \
        }                                                                          \
        _Pragma("unroll")                                                          \
        for (int i_ = 0; i_ < 4; ++i_) {                                           \
            int d0_ = 64*w + 16*i_;                                                \
            int row_ = d0_ + (lane >> 2);                                          \
            __builtin_amdgcn_global_load_lds(                                      \
                (const __attribute__((address_space(1))) void*)(vp + (size_t)row_*TT + ksv_ + vswz*8), \
                (__attribute__((address_space(3))) void*)(&Vs[BUF][d0_][0]),       \
                16, 0, 0);                                                         \
        }                                                                          \
    } while (0)

    #pragma unroll 1
    for (int phase = 0; phase < 2; ++phase) {
        const int qb = phase ? (31 - pr) : pr;
        const int qbase = qb * 128;
        const int qrow  = qbase + 16*qgp + lm;
        const int t0  = s * (qb + 1);          // this quarter's start k-tile
        const int cnt = qb + 1;                // k-tiles in this quarter

        // hoist Q fragments for this phase: lane (g,lm) holds Q[qrow][32ss+8g .. +8]
        short8v qf[16];
        #pragma unroll
        for (int ss = 0; ss < 16; ++ss)
            qf[ss] = *reinterpret_cast<const short8v*>(qp + (size_t)qrow*D + 32*ss + 8*g);

        float4v acc[32];                       // O^T: col=q=lm, rows=dims 16*dt+4g+r
        #pragma unroll
        for (int i = 0; i < 32; ++i) acc[i] = (float4v){0.f,0.f,0.f,0.f};
        float m_r = -INFINITY, l_par = 0.f;    // l_par: this lane's 8-kj partial sum

        __syncthreads();                       // prev phase's LDS reads done before re-staging
        STAGE_KV(t0, 0);

        for (int i = 0; i < cnt; ++i) {
            const int t = t0 + i;
            const int ks0 = t * KT;
            __syncthreads();                   // own vmcnt drained pre-barrier -> stage(i)
                                               // landed for all waves; reads of i-1 done
            if (i + 1 < cnt) STAGE_KV(t + 1, (i + 1) & 1);

            const short* kc = (i & 1) ? k1p : k0p;
            const short* vc = (i & 1) ? v1p : v0p;

            // S^T[kj][q]: 4 independent 8-deep MFMA chains (priority-boosted)
            float4v s0a = (float4v){0.f,0.f,0.f,0.f}, s0b = (float4v){0.f,0.f,0.f,0.f};
            float4v s1a = (float4v){0.f,0.f,0.f,0.f}, s1b = (float4v){0.f,0.f,0.f,0.f};
            __builtin_amdgcn_s_setprio(1);
            #pragma unroll
            for (int ss = 0; ss < 16; ++ss) {
                int off = (ss ^ lm) << 5;      // shorts: 32*(ss^lm)
                short8v a0 = *reinterpret_cast<const short8v*>(kc + off);
                short8v a1 = *reinterpret_cast<const short8v*>(kc + off + 8192);
                if (ss & 1) {
                    s0b = __builtin_amdgcn_mfma_f32_16x16x32_bf16(a0, qf[ss], s0b, 0, 0, 0);
                    s1b = __builtin_amdgcn_mfma_f32_16x16x32_bf16(a1, qf[ss], s1b, 0, 0, 0);
                } else {
                    s0a = __builtin_amdgcn_mfma_f32_16x16x32_bf16(a0, qf[ss], s0a, 0, 0, 0);
                    s1a = __builtin_amdgcn_mfma_f32_16x16x32_bf16(a1, qf[ss], s1a, 0, 0, 0);
                }
            }
            __builtin_amdgcn_s_setprio(0);
            float4v s0, s1;
            #pragma unroll
            for (int r = 0; r < 4; ++r) { s0[r] = s0a[r] + s0b[r]; s1[r] = s1a[r] + s1b[r]; }

            // causal mask; lane holds kj = ks0 + sigma(g,e) for q = qrow
            float p[8];
            #pragma unroll
            for (int r = 0; r < 4; ++r) {
                int kj0 = ks0 + 4*g + r;
                p[r]     = (kj0      <= qrow) ? s0[r] : -3.0e38f;
                p[r + 4] = (kj0 + 16 <= qrow) ? s1[r] : -3.0e38f;
            }
            float mx = p[0];
            #pragma unroll
            for (int i2 = 1; i2 < 8; ++i2) mx = fmaxf(mx, p[i2]);

            // defer-max: row-max shuffles + rescale only when slack exceeded (or first tile)
            if (!__all(mx <= m_r + 8.f)) {
                float mrow = fmaxf(mx, __shfl_xor(mx, 16));
                mrow = fmaxf(mrow, __shfl_xor(mrow, 32));
                mrow = fmaxf(mrow, m_r);
                float corr = __expf(m_r - mrow);   // first tile: expf(-inf)=0
                m_r = mrow;
                l_par *= corr;
                #pragma unroll
                for (int dt = 0; dt < 32; ++dt) {
                    acc[dt][0] *= corr; acc[dt][1] *= corr;
                    acc[dt][2] *= corr; acc[dt][3] *= corr;
                }
            }
            // gated exp: fully-masked entries (incl. all-masked rows where m_r==-3e38) -> 0
            #pragma unroll
            for (int i2 = 0; i2 < 8; ++i2) {
                float e = __expf(p[i2] - m_r);
                p[i2] = (p[i2] > -1.0e37f) ? e : 0.f;
                l_par += p[i2];
            }

            // P fragment (lane-local): B-operand elems = P[q=lm][sigma(g,e)], values <= e^8
            short8v pf;
            #pragma unroll
            for (int i2 = 0; i2 < 8; ++i2) pf[i2] = f2bf(p[i2]);

            // PV (O^T): A = V^T rows (full 512 dims), literal offsets, B = pf
            __builtin_amdgcn_s_setprio(1);
            #pragma unroll
            for (int dt = 0; dt < 32; ++dt) {
                short8v vf = *reinterpret_cast<const short8v*>(vc + dt*512);
                acc[dt] = __builtin_amdgcn_mfma_f32_16x16x32_bf16(vf, pf, acc[dt], 0, 0, 0);
            }
            __builtin_amdgcn_s_setprio(0);
        }

        // phase epilogue: reduce l across the row's 4 g-lanes; store UNNORMALIZED U + (m,l)
        float l = l_par + __shfl_xor(l_par, 16);
        l += __shfl_xor(l, 32);
        const int orow = qbase + 16*qgp + lm;
        short* up = Uo + (size_t)(b*TT + orow)*D;
        #pragma unroll
        for (int dt = 0; dt < 32; ++dt) {
            short4v o = { f2bf(acc[dt][0]), f2bf(acc[dt][1]),
                          f2bf(acc[dt][2]), f2bf(acc[dt][3]) };
            *reinterpret_cast<short4v*>(up + 16*dt + 4*g) = o;
        }
        if (g == 0) {                          // one writer per row (lanes 0..15)
            mo[(size_t)b*TT + orow] = m_r;
            lo[(size_t)b*TT + orow] = l;
        }
    }
    #undef STAGE_KV
}

// ============ Fused merge + output projection ============
// 256 blocks x 8 waves; block owns a 64-row strip. Stage ONCE: merged ctx tile (4-quarter
// softmax merge) into 64KB LDS with chunk-XOR swizzle j^(4*(row&15)) -> conflict-free
// b128 A-frag reads. Then a barrier-free k-loop: wave w computes cols [64w,64w+64);
// B-fragments read DIRECT from global Wo (f32->bf16 in-reg; Wo = 1MB, L2/L3-resident).
// Replaces merge_quads + gemm_out; A traffic cut 8x.
__global__ __launch_bounds__(512, 1) void gemm_out_fused(
    const __hip_bfloat16* __restrict__ U0, const __hip_bfloat16* __restrict__ U1,
    const __hip_bfloat16* __restrict__ U2, const __hip_bfloat16* __restrict__ U3,
    const float* __restrict__ mArr, const float* __restrict__ lArr,
    const float* __restrict__ W, float* __restrict__ out)
{
    __shared__ short As[64][512];              // merged ctx strip, chunk-XOR swizzled (64KB)
    const int tid = threadIdx.x;
    const int w = tid >> 6, lane = tid & 63, lm = lane & 15, g = lane >> 4;
    const int m0 = blockIdx.x * 64;
    const int BT = BB * TT;

    // merge-stage (once): thread -> row tid>>3, logical chunks (tid&7)*8 .. +8
    {
        const int row = tid >> 3;
        const int grow = m0 + row;
        float ma_ = mArr[grow],        mb_ = mArr[BT + grow];
        float mc_ = mArr[2*BT + grow], md_ = mArr[3*BT + grow];
        float ms = fmaxf(fmaxf(ma_, mb_), fmaxf(mc_, md_));
        float w0 = __expf(ma_ - ms), w1 = __expf(mb_ - ms);
        float w2 = __expf(mc_ - ms), w3 = __expf(md_ - ms);
        float l = lArr[grow]*w0 + lArr[BT + grow]*w1 + lArr[2*BT + grow]*w2 + lArr[3*BT + grow]*w3;
        float inv = 1.f / l;
        w0 *= inv; w1 *= inv; w2 *= inv; w3 *= inv;
        const size_t base = (size_t)grow * D;
        #pragma unroll
        for (int jc = 0; jc < 8; ++jc) {
            int j = (tid & 7) * 8 + jc;        // logical chunk 0..63
            size_t off = base + (size_t)j * 8;
            short8v a = *reinterpret_cast<const short8v*>((const short*)U0 + off);
            short8v b = *reinterpret_cast<const short8v*>((const short*)U1 + off);
            short8v c = *reinterpret_cast<const short8v*>((const short*)U2 + off);
            short8v d = *reinterpret_cast<const short8v*>((const short*)U3 + off);
            short8v o;
            #pragma unroll
            for (int i = 0; i < 8; ++i)
                o[i] = f2bf(bf2f(a[i])*w0 + bf2f(b[i])*w1 + bf2f(c[i])*w2 + bf2f(d[i])*w3);
            int pj = (j ^ (4 * (row & 15))) & 63;   // swizzled chunk
            *reinterpret_cast<short8v*>(&As[row][pj * 8]) = o;
        }
    }
    __syncthreads();                           // the ONLY barrier

    float4v acc[4][4];                         // [row-tile][col-tile]
    #pragma unroll
    for (int rt = 0; rt < 4; ++rt)
        #pragma unroll
        for (int nt = 0; nt < 4; ++nt) acc[rt][nt] = (float4v){0.f,0.f,0.f,0.f};

    for (int k0 = 0; k0 < 512; k0 += 64) {
        #pragma unroll
        for (int ks = 0; ks < 2; ++ks) {
            const int j = (((k0 >> 3) + 4*ks + g) ^ (4 * lm)) & 63;
            short8v a[4];
            #pragma unroll
            for (int rt = 0; rt < 4; ++rt)
                a[rt] = *reinterpret_cast<const short8v*>(&As[16*rt + lm][j * 8]);
            #pragma unroll
            for (int nt = 0; nt < 4; ++nt) {
                const float* wp = W + (size_t)(64*w + 16*nt + lm)*512 + k0 + 32*ks + 8*g;
                float4 b0 = *reinterpret_cast<const float4*>(wp);
                float4 b1 = *reinterpret_cast<const float4*>(wp + 4);
                short8v bv = { f2bf(b0.x), f2bf(b0.y), f2bf(b0.z), f2bf(b0.w),
                               f2bf(b1.x), f2bf(b1.y), f2bf(b1.z), f2bf(b1.w) };
                #pragma unroll
                for (int rt = 0; rt < 4; ++rt)
                    acc[rt][nt] = __builtin_amdgcn_mfma_f32_16x16x32_bf16(a[rt], bv, acc[rt][nt], 0, 0, 0);
            }
        }
    }

    #pragma unroll
    for (int rt = 0; rt < 4; ++rt)
        #pragma unroll
        for (int nt = 0; nt < 4; ++nt)
            #pragma unroll
            for (int r = 0; r < 4; ++r) {
                int row = m0 + 16*rt + 4*g + r;
                int col = 64*w + 16*nt + lm;
                out[(size_t)row*512 + col] = acc[rt][nt][r];
            }
}

extern "C" void kernel_launch(void* const* d_in, const int* in_sizes, int n_in,
                              void* d_out, int out_size, void* d_ws, size_t ws_size,
                              hipStream_t stream) {
    const float* x  = (const float*)d_in[0];
    const float* Wq = (const float*)d_in[1];
    const float* Wk = (const float*)d_in[2];
    const float* Wv = (const float*)d_in[3];
    const float* Wo = (const float*)d_in[4];
    float* out = (float*)d_out;

    const size_t n = (size_t)BB * TT * D;                 // 8.4M elems
    __hip_bfloat16* qb_ = (__hip_bfloat16*)d_ws;
    __hip_bfloat16* kb_ = qb_ + n;
    __hip_bfloat16* vt_ = kb_ + n;                        // sigma-permuted V^T (written by gemm_qkv)
    __hip_bfloat16* U0  = vt_ + n;                        // 4 x 16.8MB bf16 quarters
    __hip_bfloat16* U1  = U0 + n;
    __hip_bfloat16* U2  = U1 + n;
    __hip_bfloat16* U3  = U2 + n;
    float* mArr = (float*)(U3 + n);                       // 4 x BT f32
    float* lArr = mArr + (size_t)4 * BB * TT;             // 4 x BT f32

    gemm_qkv<<<dim3(256, 8), 256, 0, stream>>>(x, Wq, Wk, Wv, qb_, kb_, vt_);
    attn_split<<<dim3(64 * BB), 512, 0, stream>>>(qb_, kb_, vt_, U0, U1, U2, U3, mArr, lArr);
    gemm_out_fused<<<dim3(256), 512, 0, stream>>>(U0, U1, U2, U3, mArr, lArr, Wo, out);
}

// Round 19
// 258.257 us; speedup vs baseline: 1.0217x; 1.0217x over previous
//
#include <hip/hip_runtime.h>
#include <hip/hip_bf16.h>
#include <math.h>

#define D 512
#define BB 4
#define TT 4096
#define KT 32

typedef __attribute__((ext_vector_type(8))) short short8v;
typedef __attribute__((ext_vector_type(4))) short short4v;
typedef __attribute__((ext_vector_type(4))) float float4v;

__device__ inline short f2bf(float x) {
    __hip_bfloat16 h = __float2bfloat16(x);
    return *reinterpret_cast<short*>(&h);
}
__device__ inline float bf2f(short s) {
    __hip_bfloat16 h = *reinterpret_cast<__hip_bfloat16*>(&s);
    return __bfloat162float(h);
}

// ============ Fused QKV projection + V-transpose, 128-row m-tile ============
// C_z[t][e] = alpha_z * sum_d x[t][d] * W_z[e][d], bf16 out. x staged ONCE per k-step;
// 128-row tile halves W panel re-reads vs 64-row (393MB vs 786MB L2 traffic).
// q,k row-major; v written directly into sigma-permuted transposed vt (R17-verified path,
// extended to 128-t tiles).
__global__ __launch_bounds__(256) void gemm_qkv(
    const float* __restrict__ x,
    const float* __restrict__ Wq, const float* __restrict__ Wk, const float* __restrict__ Wv,
    __hip_bfloat16* __restrict__ q, __hip_bfloat16* __restrict__ k, __hip_bfloat16* __restrict__ vt)
{
    __shared__ short As[128][72];      // +8 bf16 pad -> conflict-floor b128 reads (18.4KB)
    __shared__ short Bs[3][64][72];    // 27.6KB
    __shared__ short Ts[64][130];      // V-tile transpose buffer [d_local][t_local] (16.6KB)
    const int tid = threadIdx.x;
    const int m0 = blockIdx.x * 128, n0 = blockIdx.y * 64;
    const int w = tid >> 6, lane = tid & 63, lm = lane & 15, g = lane >> 4;

    float4v acc[3][2][4];              // [z][m-subtile][n-tile]
    #pragma unroll
    for (int z = 0; z < 3; ++z)
        #pragma unroll
        for (int mt = 0; mt < 2; ++mt)
            #pragma unroll
            for (int i = 0; i < 4; ++i) acc[z][mt][i] = (float4v){0.f,0.f,0.f,0.f};

    for (int k0 = 0; k0 < 512; k0 += 64) {
        __syncthreads();
        #pragma unroll
        for (int u = 0; u < 8; ++u) {          // stage A (x, 128 rows), convert f32->bf16
            int ch = tid + 256*u;              // 2048 float4-chunks
            int r = ch >> 4, c = (ch & 15) * 4;
            float4 xv = *reinterpret_cast<const float4*>(x + (size_t)(m0 + r)*512 + k0 + c);
            short4v sv = { f2bf(xv.x), f2bf(xv.y), f2bf(xv.z), f2bf(xv.w) };
            *reinterpret_cast<short4v*>(&As[r][c]) = sv;
        }
        #pragma unroll
        for (int z = 0; z < 3; ++z) {          // stage B for all 3 weight matrices
            const float* W = (z == 0) ? Wq : (z == 1) ? Wk : Wv;
            #pragma unroll
            for (int u = 0; u < 4; ++u) {
                int ch = tid + 256*u;
                int r = ch >> 4, c = (ch & 15) * 4;
                float4 wv = *reinterpret_cast<const float4*>(W + (size_t)(n0 + r)*512 + k0 + c);
                short4v sv = { f2bf(wv.x), f2bf(wv.y), f2bf(wv.z), f2bf(wv.w) };
                *reinterpret_cast<short4v*>(&Bs[z][r][c]) = sv;
            }
        }
        __syncthreads();
        #pragma unroll
        for (int ks = 0; ks < 2; ++ks) {
            short8v a[2];
            #pragma unroll
            for (int mt = 0; mt < 2; ++mt)
                a[mt] = *reinterpret_cast<const short8v*>(&As[64*mt + 16*w + lm][ks*32 + 8*g]);
            #pragma unroll
            for (int z = 0; z < 3; ++z)
                #pragma unroll
                for (int nt = 0; nt < 4; ++nt) {
                    short8v bv = *reinterpret_cast<const short8v*>(&Bs[z][16*nt + lm][ks*32 + 8*g]);
                    #pragma unroll
                    for (int mt = 0; mt < 2; ++mt)
                        acc[z][mt][nt] = __builtin_amdgcn_mfma_f32_16x16x32_bf16(a[mt], bv, acc[z][mt][nt], 0, 0, 0);
                }
        }
    }

    // q, k: direct row-major writes (D layout: row = 4*(lane>>4)+reg, col = lane&15)
    #pragma unroll
    for (int z = 0; z < 2; ++z) {
        __hip_bfloat16* C = (z == 0) ? q : k;
        const float alpha = (z == 0) ? 0.044194173824159216f : 1.f;   // fold 1/sqrt(512) into q
        #pragma unroll
        for (int mt = 0; mt < 2; ++mt)
            #pragma unroll
            for (int nt = 0; nt < 4; ++nt)
                #pragma unroll
                for (int r = 0; r < 4; ++r) {
                    int row = m0 + 64*mt + 16*w + 4*g + r;
                    int col = n0 + 16*nt + lm;
                    C[(size_t)row*512 + col] = __float2bfloat16(acc[z][mt][nt][r] * alpha);
                }
    }

    // v: transposed store into Ts[d_local][t_local] (bf16), then sigma-permuted coalesced write
    #pragma unroll
    for (int mt = 0; mt < 2; ++mt)
        #pragma unroll
        for (int nt = 0; nt < 4; ++nt)
            #pragma unroll
            for (int r = 0; r < 4; ++r)
                Ts[16*nt + lm][64*mt + 16*w + 4*g + r] = f2bf(acc[2][mt][nt][r]);
    __syncthreads();

    {
        const int dloc = tid >> 2;             // 0..63
        const int bb   = m0 >> 12;             // batch (TT=4096; 128-row tiles never straddle)
        const int tb   = m0 & (TT - 1);
        #pragma unroll
        for (int qq = 0; qq < 2; ++qq) {
            const int qs = (tid & 3) + 4*qq;   // 16-t chunk 0..7
            short tmp[16];
            #pragma unroll
            for (int i = 0; i < 16; ++i) {
                int tp = qs*16 + i;            // 0..127
                int blk = tp & 0x60;           // 32-t block base
                int p = tp & 31;
                int tloc = blk + 16*((p & 7) >> 2) + 4*(p >> 3) + (p & 3);   // inverse sigma
                tmp[i] = Ts[dloc][tloc];
            }
            short* dst = (short*)vt + (size_t)bb*D*TT + (size_t)(n0 + dloc)*TT + tb + qs*16;
            *reinterpret_cast<short8v*>(dst)     = *reinterpret_cast<short8v*>(&tmp[0]);
            *reinterpret_cast<short8v*>(dst + 8) = *reinterpret_cast<short8v*>(&tmp[8]);
        }
    }
}

// ============ Flash attention, QB=128, 4-way split-K + triangle pairing (R15-R17 verified) ============
__global__ __launch_bounds__(512, 1) void attn_split(
    const __hip_bfloat16* __restrict__ qg, const __hip_bfloat16* __restrict__ kg,
    const __hip_bfloat16* __restrict__ vtg,
    __hip_bfloat16* __restrict__ U0, __hip_bfloat16* __restrict__ U1,
    __hip_bfloat16* __restrict__ U2, __hip_bfloat16* __restrict__ U3,
    float* __restrict__ mArr, float* __restrict__ lArr)
{
    __shared__ short Ks[2][KT][512];           // 64KB; row r chunk c holds K chunk c^(4*(r&15))
    __shared__ short Vs[2][512][32];           // 64KB; row d chunk c holds vt chunk c^((d>>1)&3)

    const int tid = threadIdx.x;
    const int w = tid >> 6, lane = tid & 63, lm = lane & 15, g = lane >> 4;
    const int qgp = w;                         // q-group 0..7 (full-d wave)
    const int idx = blockIdx.x;
    const int b  = idx & 3;                    // batch -> XCD spread
    const int u  = idx >> 2;
    const int pr = u >> 2;                     // pair index 0..15
    const int s  = u & 3;                      // key-quarter

    const short* qp = (const short*)qg  + (size_t)b*TT*D;
    const short* kp = (const short*)kg  + (size_t)b*TT*D;
    const short* vp = (const short*)vtg + (size_t)b*D*TT;

    short* Uo = (short*)((s == 0) ? U0 : (s == 1) ? U1 : (s == 2) ? U2 : U3);
    float* mo = mArr + (size_t)s * BB * TT;
    float* lo = lArr + (size_t)s * BB * TT;

    const int vswz = (lane & 3) ^ ((lane >> 3) & 3);   // V stage: source chunk for this lane

    // per-lane LDS base pointers (element = short)
    const short* k0p = &Ks[0][lm][g*8];        // QK read: kc + 32*(ss^lm); second subtile +8192
    const short* k1p = &Ks[1][lm][g*8];
    const int vcid = g ^ ((lm >> 1) & 3);
    const short* v0p = &Vs[0][lm][vcid*8];     // PV read: vc + dt*512 (literal), dt 0..31
    const short* v1p = &Vs[1][lm][vcid*8];

    // stage k-tile T (global index) into buffer BUF; 8 waves split the 64 DMA instrs
    #define STAGE_KV(T, BUF) do {                                                  \
        const short* kt_ = kp + (size_t)(T) * KT * D;                              \
        const int ksv_ = (T) * KT;                                                 \
        _Pragma("unroll")                                                          \
        for (int i_ = 0; i_ < 4; ++i_) {                                           \
            int r_ = 4*w + i_;                                                     \
            int c_ = (lane ^ ((r_ & 15) << 2)) & 63;                               \
            __builtin_amdgcn_global_load_lds(                                      \
                (const __attribute__((address_space(1))) void*)(kt_ + (size_t)r_*D + c_*8), \
                (__attribute__((address_space(3))) void*)(&Ks[BUF][r_][0]),        \
                16, 0, 0);                                                         \
        }                                                                          \
        _Pragma("unroll")                                                          \
        for (int i_ = 0; i_ < 4; ++i_) {                                           \
            int d0_ = 64*w + 16*i_;                                                \
            int row_ = d0_ + (lane >> 2);                                          \
            __builtin_amdgcn_global_load_lds(                                      \
                (const __attribute__((address_space(1))) void*)(vp + (size_t)row_*TT + ksv_ + vswz*8), \
                (__attribute__((address_space(3))) void*)(&Vs[BUF][d0_][0]),       \
                16, 0, 0);                                                         \
        }                                                                          \
    } while (0)

    #pragma unroll 1
    for (int phase = 0; phase < 2; ++phase) {
        const int qb = phase ? (31 - pr) : pr;
        const int qbase = qb * 128;
        const int qrow  = qbase + 16*qgp + lm;
        const int t0  = s * (qb + 1);          // this quarter's start k-tile
        const int cnt = qb + 1;                // k-tiles in this quarter

        // hoist Q fragments for this phase: lane (g,lm) holds Q[qrow][32ss+8g .. +8]
        short8v qf[16];
        #pragma unroll
        for (int ss = 0; ss < 16; ++ss)
            qf[ss] = *reinterpret_cast<const short8v*>(qp + (size_t)qrow*D + 32*ss + 8*g);

        float4v acc[32];                       // O^T: col=q=lm, rows=dims 16*dt+4g+r
        #pragma unroll
        for (int i = 0; i < 32; ++i) acc[i] = (float4v){0.f,0.f,0.f,0.f};
        float m_r = -INFINITY, l_par = 0.f;    // l_par: this lane's 8-kj partial sum

        __syncthreads();                       // prev phase's LDS reads done before re-staging
        STAGE_KV(t0, 0);

        for (int i = 0; i < cnt; ++i) {
            const int t = t0 + i;
            const int ks0 = t * KT;
            __syncthreads();                   // own vmcnt drained pre-barrier -> stage(i)
                                               // landed for all waves; reads of i-1 done
            if (i + 1 < cnt) STAGE_KV(t + 1, (i + 1) & 1);

            const short* kc = (i & 1) ? k1p : k0p;
            const short* vc = (i & 1) ? v1p : v0p;

            // S^T[kj][q]: 4 independent 8-deep MFMA chains (priority-boosted)
            float4v s0a = (float4v){0.f,0.f,0.f,0.f}, s0b = (float4v){0.f,0.f,0.f,0.f};
            float4v s1a = (float4v){0.f,0.f,0.f,0.f}, s1b = (float4v){0.f,0.f,0.f,0.f};
            __builtin_amdgcn_s_setprio(1);
            #pragma unroll
            for (int ss = 0; ss < 16; ++ss) {
                int off = (ss ^ lm) << 5;      // shorts: 32*(ss^lm)
                short8v a0 = *reinterpret_cast<const short8v*>(kc + off);
                short8v a1 = *reinterpret_cast<const short8v*>(kc + off + 8192);
                if (ss & 1) {
                    s0b = __builtin_amdgcn_mfma_f32_16x16x32_bf16(a0, qf[ss], s0b, 0, 0, 0);
                    s1b = __builtin_amdgcn_mfma_f32_16x16x32_bf16(a1, qf[ss], s1b, 0, 0, 0);
                } else {
                    s0a = __builtin_amdgcn_mfma_f32_16x16x32_bf16(a0, qf[ss], s0a, 0, 0, 0);
                    s1a = __builtin_amdgcn_mfma_f32_16x16x32_bf16(a1, qf[ss], s1a, 0, 0, 0);
                }
            }
            __builtin_amdgcn_s_setprio(0);
            float4v s0, s1;
            #pragma unroll
            for (int r = 0; r < 4; ++r) { s0[r] = s0a[r] + s0b[r]; s1[r] = s1a[r] + s1b[r]; }

            // causal mask; lane holds kj = ks0 + sigma(g,e) for q = qrow
            float p[8];
            #pragma unroll
            for (int r = 0; r < 4; ++r) {
                int kj0 = ks0 + 4*g + r;
                p[r]     = (kj0      <= qrow) ? s0[r] : -3.0e38f;
                p[r + 4] = (kj0 + 16 <= qrow) ? s1[r] : -3.0e38f;
            }
            float mx = p[0];
            #pragma unroll
            for (int i2 = 1; i2 < 8; ++i2) mx = fmaxf(mx, p[i2]);

            // defer-max: row-max shuffles + rescale only when slack exceeded (or first tile)
            if (!__all(mx <= m_r + 8.f)) {
                float mrow = fmaxf(mx, __shfl_xor(mx, 16));
                mrow = fmaxf(mrow, __shfl_xor(mrow, 32));
                mrow = fmaxf(mrow, m_r);
                float corr = __expf(m_r - mrow);   // first tile: expf(-inf)=0
                m_r = mrow;
                l_par *= corr;
                #pragma unroll
                for (int dt = 0; dt < 32; ++dt) {
                    acc[dt][0] *= corr; acc[dt][1] *= corr;
                    acc[dt][2] *= corr; acc[dt][3] *= corr;
                }
            }
            // gated exp: fully-masked entries (incl. all-masked rows where m_r==-3e38) -> 0
            #pragma unroll
            for (int i2 = 0; i2 < 8; ++i2) {
                float e = __expf(p[i2] - m_r);
                p[i2] = (p[i2] > -1.0e37f) ? e : 0.f;
                l_par += p[i2];
            }

            // P fragment (lane-local): B-operand elems = P[q=lm][sigma(g,e)], values <= e^8
            short8v pf;
            #pragma unroll
            for (int i2 = 0; i2 < 8; ++i2) pf[i2] = f2bf(p[i2]);

            // PV (O^T): A = V^T rows (full 512 dims), literal offsets, B = pf
            __builtin_amdgcn_s_setprio(1);
            #pragma unroll
            for (int dt = 0; dt < 32; ++dt) {
                short8v vf = *reinterpret_cast<const short8v*>(vc + dt*512);
                acc[dt] = __builtin_amdgcn_mfma_f32_16x16x32_bf16(vf, pf, acc[dt], 0, 0, 0);
            }
            __builtin_amdgcn_s_setprio(0);
        }

        // phase epilogue: reduce l across the row's 4 g-lanes; store UNNORMALIZED U + (m,l)
        float l = l_par + __shfl_xor(l_par, 16);
        l += __shfl_xor(l, 32);
        const int orow = qbase + 16*qgp + lm;
        short* up = Uo + (size_t)(b*TT + orow)*D;
        #pragma unroll
        for (int dt = 0; dt < 32; ++dt) {
            short4v o = { f2bf(acc[dt][0]), f2bf(acc[dt][1]),
                          f2bf(acc[dt][2]), f2bf(acc[dt][3]) };
            *reinterpret_cast<short4v*>(up + 16*dt + 4*g) = o;
        }
        if (g == 0) {                          // one writer per row (lanes 0..15)
            mo[(size_t)b*TT + orow] = m_r;
            lo[(size_t)b*TT + orow] = l;
        }
    }
    #undef STAGE_KV
}

// ============ Merge the four key-quarters: O = sum_s U_s*w_s / sum_s l_s*w_s ============
__global__ __launch_bounds__(256) void merge_quads(
    const __hip_bfloat16* __restrict__ U0, const __hip_bfloat16* __restrict__ U1,
    const __hip_bfloat16* __restrict__ U2, const __hip_bfloat16* __restrict__ U3,
    const float* __restrict__ mArr, const float* __restrict__ lArr,
    __hip_bfloat16* __restrict__ ctx)
{
    const int BT = BB * TT;
    const int gidx = blockIdx.x * 256 + threadIdx.x;   // one thread per 8 cols
    const int row = gidx >> 6;
    const int c = (gidx & 63) * 8;
    float m0 = mArr[row], m1 = mArr[BT + row], m2 = mArr[2*BT + row], m3 = mArr[3*BT + row];
    float ms = fmaxf(fmaxf(m0, m1), fmaxf(m2, m3));
    float w0 = __expf(m0 - ms), w1 = __expf(m1 - ms);
    float w2 = __expf(m2 - ms), w3 = __expf(m3 - ms);
    float l = lArr[row]*w0 + lArr[BT + row]*w1 + lArr[2*BT + row]*w2 + lArr[3*BT + row]*w3;
    float inv = 1.f / l;
    w0 *= inv; w1 *= inv; w2 *= inv; w3 *= inv;
    size_t off = (size_t)row * D + c;
    short8v a = *reinterpret_cast<const short8v*>((const short*)U0 + off);
    short8v b = *reinterpret_cast<const short8v*>((const short*)U1 + off);
    short8v d = *reinterpret_cast<const short8v*>((const short*)U2 + off);
    short8v e = *reinterpret_cast<const short8v*>((const short*)U3 + off);
    short8v o;
    #pragma unroll
    for (int i = 0; i < 8; ++i)
        o[i] = f2bf(bf2f(a[i])*w0 + bf2f(b[i])*w1 + bf2f(d[i])*w2 + bf2f(e[i])*w3);
    *reinterpret_cast<short8v*>((short*)ctx + off) = o;
}

// ============ Output projection: d_out[t][e] = sum_d ctx[t][d] * Wo[e][d], f32 out ============
__global__ __launch_bounds__(256) void gemm_out(
    const __hip_bfloat16* __restrict__ Ab, const float* __restrict__ W,
    float* __restrict__ Cf)
{
    __shared__ short As[64][72];
    __shared__ short Bs[64][72];
    const int tid = threadIdx.x;
    const int m0 = blockIdx.x * 64, n0 = blockIdx.y * 64;
    const int w = tid >> 6, lane = tid & 63, lm = lane & 15, g = lane >> 4;
    const short* Ap = (const short*)Ab;

    float4v acc[4];
    #pragma unroll
    for (int i = 0; i < 4; ++i) acc[i] = (float4v){0.f,0.f,0.f,0.f};

    for (int k0 = 0; k0 < 512; k0 += 64) {
        __syncthreads();
        #pragma unroll
        for (int u = 0; u < 2; ++u) {          // stage A (bf16 ctx)
            int ch = tid + 256*u;
            int r = ch >> 3, c = (ch & 7) * 8;
            *reinterpret_cast<short8v*>(&As[r][c]) =
                *reinterpret_cast<const short8v*>(Ap + (size_t)(m0 + r)*512 + k0 + c);
        }
        #pragma unroll
        for (int u = 0; u < 4; ++u) {          // stage B (Wo f32 -> bf16)
            int ch = tid + 256*u;
            int r = ch >> 4, c = (ch & 15) * 4;
            float4 wv = *reinterpret_cast<const float4*>(W + (size_t)(n0 + r)*512 + k0 + c);
            short4v sv = { f2bf(wv.x), f2bf(wv.y), f2bf(wv.z), f2bf(wv.w) };
            *reinterpret_cast<short4v*>(&Bs[r][c]) = sv;
        }
        __syncthreads();
        #pragma unroll
        for (int ks = 0; ks < 2; ++ks) {
            short8v a = *reinterpret_cast<const short8v*>(&As[16*w + lm][ks*32 + 8*g]);
            #pragma unroll
            for (int nt = 0; nt < 4; ++nt) {
                short8v bv = *reinterpret_cast<const short8v*>(&Bs[16*nt + lm][ks*32 + 8*g]);
                acc[nt] = __builtin_amdgcn_mfma_f32_16x16x32_bf16(a, bv, acc[nt], 0, 0, 0);
            }
        }
    }
    #pragma unroll
    for (int nt = 0; nt < 4; ++nt)
        #pragma unroll
        for (int r = 0; r < 4; ++r) {
            int row = m0 + 16*w + 4*g + r;
            int col = n0 + 16*nt + lm;
            Cf[(size_t)row*512 + col] = acc[nt][r];
        }
}

extern "C" void kernel_launch(void* const* d_in, const int* in_sizes, int n_in,
                              void* d_out, int out_size, void* d_ws, size_t ws_size,
                              hipStream_t stream) {
    const float* x  = (const float*)d_in[0];
    const float* Wq = (const float*)d_in[1];
    const float* Wk = (const float*)d_in[2];
    const float* Wv = (const float*)d_in[3];
    const float* Wo = (const float*)d_in[4];
    float* out = (float*)d_out;

    const size_t n = (size_t)BB * TT * D;                 // 8.4M elems
    __hip_bfloat16* qb_  = (__hip_bfloat16*)d_ws;
    __hip_bfloat16* kb_  = qb_ + n;
    __hip_bfloat16* vt_  = kb_ + n;                       // sigma-permuted V^T (written by gemm_qkv)
    __hip_bfloat16* ctxb = vt_ + n;
    __hip_bfloat16* U1   = ctxb + n;                      // 3 x 16.8MB bf16
    __hip_bfloat16* U2   = U1 + n;
    __hip_bfloat16* U3   = U2 + n;
    float* mArr = (float*)(U3 + n);                       // 4 x BT f32 = 1MB
    float* lArr = mArr + (size_t)4 * BB * TT;             // 4 x BT f32 = 1MB
    __hip_bfloat16* U0 = (__hip_bfloat16*)out;            // d_out as scratch (overwritten later)

    gemm_qkv<<<dim3(128, 8), 256, 0, stream>>>(x, Wq, Wk, Wv, qb_, kb_, vt_);
    attn_split<<<dim3(64 * BB), 512, 0, stream>>>(qb_, kb_, vt_, U0, U1, U2, U3, mArr, lArr);
    merge_quads<<<dim3(BB * TT / 4), 256, 0, stream>>>(U0, U1, U2, U3, mArr, lArr, ctxb);
    gemm_out<<<dim3(256, 8, 1), 256, 0, stream>>>(ctxb, Wo, out);
}

// Round 20
// 239.304 us; speedup vs baseline: 1.1027x; 1.0792x over previous
//
#include <hip/hip_runtime.h>
#include <hip/hip_bf16.h>
#include <math.h>

#define D 512
#define BB 4
#define TT 4096
#define KT 32

typedef __attribute__((ext_vector_type(8))) short short8v;
typedef __attribute__((ext_vector_type(4))) short short4v;
typedef __attribute__((ext_vector_type(4))) float float4v;

__device__ inline short f2bf(float x) {
    __hip_bfloat16 h = __float2bfloat16(x);
    return *reinterpret_cast<short*>(&h);
}
__device__ inline float bf2f(short s) {
    __hip_bfloat16 h = *reinterpret_cast<__hip_bfloat16*>(&s);
    return __bfloat162float(h);
}

// ============ Fused QKV projection + V-transpose (R17-verified, 64-row tile) ============
__global__ __launch_bounds__(256) void gemm_qkv(
    const float* __restrict__ x,
    const float* __restrict__ Wq, const float* __restrict__ Wk, const float* __restrict__ Wv,
    __hip_bfloat16* __restrict__ q, __hip_bfloat16* __restrict__ k, __hip_bfloat16* __restrict__ vt)
{
    __shared__ short As[64][72];       // +8 bf16 pad -> conflict-floor b128 reads
    __shared__ short Bs[3][64][72];
    __shared__ short Ts[64][66];       // V-tile transpose buffer [d_local][t_local]
    const int tid = threadIdx.x;
    const int m0 = blockIdx.x * 64, n0 = blockIdx.y * 64;
    const int w = tid >> 6, lane = tid & 63, lm = lane & 15, g = lane >> 4;

    float4v acc[3][4];
    #pragma unroll
    for (int z = 0; z < 3; ++z)
        #pragma unroll
        for (int i = 0; i < 4; ++i) acc[z][i] = (float4v){0.f,0.f,0.f,0.f};

    for (int k0 = 0; k0 < 512; k0 += 64) {
        __syncthreads();
        #pragma unroll
        for (int u = 0; u < 4; ++u) {          // stage A (x), convert f32->bf16, ONCE
            int ch = tid + 256*u;
            int r = ch >> 4, c = (ch & 15) * 4;
            float4 xv = *reinterpret_cast<const float4*>(x + (size_t)(m0 + r)*512 + k0 + c);
            short4v sv = { f2bf(xv.x), f2bf(xv.y), f2bf(xv.z), f2bf(xv.w) };
            *reinterpret_cast<short4v*>(&As[r][c]) = sv;
        }
        #pragma unroll
        for (int z = 0; z < 3; ++z) {          // stage B for all 3 weight matrices
            const float* W = (z == 0) ? Wq : (z == 1) ? Wk : Wv;
            #pragma unroll
            for (int u = 0; u < 4; ++u) {
                int ch = tid + 256*u;
                int r = ch >> 4, c = (ch & 15) * 4;
                float4 wv = *reinterpret_cast<const float4*>(W + (size_t)(n0 + r)*512 + k0 + c);
                short4v sv = { f2bf(wv.x), f2bf(wv.y), f2bf(wv.z), f2bf(wv.w) };
                *reinterpret_cast<short4v*>(&Bs[z][r][c]) = sv;
            }
        }
        __syncthreads();
        #pragma unroll
        for (int ks = 0; ks < 2; ++ks) {
            short8v a = *reinterpret_cast<const short8v*>(&As[16*w + lm][ks*32 + 8*g]);
            #pragma unroll
            for (int z = 0; z < 3; ++z)
                #pragma unroll
                for (int nt = 0; nt < 4; ++nt) {
                    short8v bv = *reinterpret_cast<const short8v*>(&Bs[z][16*nt + lm][ks*32 + 8*g]);
                    acc[z][nt] = __builtin_amdgcn_mfma_f32_16x16x32_bf16(a, bv, acc[z][nt], 0, 0, 0);
                }
        }
    }

    // q, k: direct row-major writes (D layout: row = 4*(lane>>4)+reg, col = lane&15)
    #pragma unroll
    for (int z = 0; z < 2; ++z) {
        __hip_bfloat16* C = (z == 0) ? q : k;
        const float alpha = (z == 0) ? 0.044194173824159216f : 1.f;   // fold 1/sqrt(512) into q
        #pragma unroll
        for (int nt = 0; nt < 4; ++nt)
            #pragma unroll
            for (int r = 0; r < 4; ++r) {
                int row = m0 + 16*w + 4*g + r;
                int col = n0 + 16*nt + lm;
                C[(size_t)row*512 + col] = __float2bfloat16(acc[z][nt][r] * alpha);
            }
    }

    // v: transposed store into Ts[d_local][t_local] (bf16), then sigma-permuted coalesced write
    #pragma unroll
    for (int nt = 0; nt < 4; ++nt)
        #pragma unroll
        for (int r = 0; r < 4; ++r)
            Ts[16*nt + lm][16*w + 4*g + r] = f2bf(acc[2][nt][r]);
    __syncthreads();

    {
        const int dloc = tid >> 2;             // 0..63
        const int qs   = tid & 3;              // 16-t chunk
        const int bb   = m0 >> 12;             // batch (TT=4096; 64-row tiles never straddle)
        const int tb   = m0 & (TT - 1);
        short tmp[16];
        #pragma unroll
        for (int i = 0; i < 16; ++i) {
            int tp = qs*16 + i;
            int blk = tp & 32;
            int p = tp & 31;
            int tloc = blk + 16*((p & 7) >> 2) + 4*(p >> 3) + (p & 3);   // inverse sigma perm
            tmp[i] = Ts[dloc][tloc];
        }
        short* dst = (short*)vt + (size_t)bb*D*TT + (size_t)(n0 + dloc)*TT + tb + qs*16;
        *reinterpret_cast<short8v*>(dst)     = *reinterpret_cast<short8v*>(&tmp[0]);
        *reinterpret_cast<short8v*>(dst + 8) = *reinterpret_cast<short8v*>(&tmp[8]);
    }
}

// ============ Flash attention, QB=128, 4-way split-K + triangle pairing (R15-R17 verified) ============
__global__ __launch_bounds__(512, 1) void attn_split(
    const __hip_bfloat16* __restrict__ qg, const __hip_bfloat16* __restrict__ kg,
    const __hip_bfloat16* __restrict__ vtg,
    __hip_bfloat16* __restrict__ U0, __hip_bfloat16* __restrict__ U1,
    __hip_bfloat16* __restrict__ U2, __hip_bfloat16* __restrict__ U3,
    float* __restrict__ mArr, float* __restrict__ lArr)
{
    __shared__ short Ks[2][KT][512];           // 64KB; row r chunk c holds K chunk c^(4*(r&15))
    __shared__ short Vs[2][512][32];           // 64KB; row d chunk c holds vt chunk c^((d>>1)&3)

    const int tid = threadIdx.x;
    const int w = tid >> 6, lane = tid & 63, lm = lane & 15, g = lane >> 4;
    const int qgp = w;                         // q-group 0..7 (full-d wave)
    const int idx = blockIdx.x;
    const int b  = idx & 3;                    // batch -> XCD spread
    const int u  = idx >> 2;
    const int pr = u >> 2;                     // pair index 0..15
    const int s  = u & 3;                      // key-quarter

    const short* qp = (const short*)qg  + (size_t)b*TT*D;
    const short* kp = (const short*)kg  + (size_t)b*TT*D;
    const short* vp = (const short*)vtg + (size_t)b*D*TT;

    short* Uo = (short*)((s == 0) ? U0 : (s == 1) ? U1 : (s == 2) ? U2 : U3);
    float* mo = mArr + (size_t)s * BB * TT;
    float* lo = lArr + (size_t)s * BB * TT;

    const int vswz = (lane & 3) ^ ((lane >> 3) & 3);   // V stage: source chunk for this lane

    // per-lane LDS base pointers (element = short)
    const short* k0p = &Ks[0][lm][g*8];        // QK read: kc + 32*(ss^lm); second subtile +8192
    const short* k1p = &Ks[1][lm][g*8];
    const int vcid = g ^ ((lm >> 1) & 3);
    const short* v0p = &Vs[0][lm][vcid*8];     // PV read: vc + dt*512 (literal), dt 0..31
    const short* v1p = &Vs[1][lm][vcid*8];

    // stage k-tile T (global index) into buffer BUF; 8 waves split the 64 DMA instrs
    #define STAGE_KV(T, BUF) do {                                                  \
        const short* kt_ = kp + (size_t)(T) * KT * D;                              \
        const int ksv_ = (T) * KT;                                                 \
        _Pragma("unroll")                                                          \
        for (int i_ = 0; i_ < 4; ++i_) {                                           \
            int r_ = 4*w + i_;                                                     \
            int c_ = (lane ^ ((r_ & 15) << 2)) & 63;                               \
            __builtin_amdgcn_global_load_lds(                                      \
                (const __attribute__((address_space(1))) void*)(kt_ + (size_t)r_*D + c_*8), \
                (__attribute__((address_space(3))) void*)(&Ks[BUF][r_][0]),        \
                16, 0, 0);                                                         \
        }                                                                          \
        _Pragma("unroll")                                                          \
        for (int i_ = 0; i_ < 4; ++i_) {                                           \
            int d0_ = 64*w + 16*i_;                                                \
            int row_ = d0_ + (lane >> 2);                                          \
            __builtin_amdgcn_global_load_lds(                                      \
                (const __attribute__((address_space(1))) void*)(vp + (size_t)row_*TT + ksv_ + vswz*8), \
                (__attribute__((address_space(3))) void*)(&Vs[BUF][d0_][0]),       \
                16, 0, 0);                                                         \
        }                                                                          \
    } while (0)

    #pragma unroll 1
    for (int phase = 0; phase < 2; ++phase) {
        const int qb = phase ? (31 - pr) : pr;
        const int qbase = qb * 128;
        const int qrow  = qbase + 16*qgp + lm;
        const int t0  = s * (qb + 1);          // this quarter's start k-tile
        const int cnt = qb + 1;                // k-tiles in this quarter

        // hoist Q fragments for this phase: lane (g,lm) holds Q[qrow][32ss+8g .. +8]
        short8v qf[16];
        #pragma unroll
        for (int ss = 0; ss < 16; ++ss)
            qf[ss] = *reinterpret_cast<const short8v*>(qp + (size_t)qrow*D + 32*ss + 8*g);

        float4v acc[32];                       // O^T: col=q=lm, rows=dims 16*dt+4g+r
        #pragma unroll
        for (int i = 0; i < 32; ++i) acc[i] = (float4v){0.f,0.f,0.f,0.f};
        float m_r = -INFINITY, l_par = 0.f;    // l_par: this lane's 8-kj partial sum

        __syncthreads();                       // prev phase's LDS reads done before re-staging
        STAGE_KV(t0, 0);

        for (int i = 0; i < cnt; ++i) {
            const int t = t0 + i;
            const int ks0 = t * KT;
            __syncthreads();                   // own vmcnt drained pre-barrier -> stage(i)
                                               // landed for all waves; reads of i-1 done
            if (i + 1 < cnt) STAGE_KV(t + 1, (i + 1) & 1);

            const short* kc = (i & 1) ? k1p : k0p;
            const short* vc = (i & 1) ? v1p : v0p;

            // S^T[kj][q]: 4 independent 8-deep MFMA chains (priority-boosted)
            float4v s0a = (float4v){0.f,0.f,0.f,0.f}, s0b = (float4v){0.f,0.f,0.f,0.f};
            float4v s1a = (float4v){0.f,0.f,0.f,0.f}, s1b = (float4v){0.f,0.f,0.f,0.f};
            __builtin_amdgcn_s_setprio(1);
            #pragma unroll
            for (int ss = 0; ss < 16; ++ss) {
                int off = (ss ^ lm) << 5;      // shorts: 32*(ss^lm)
                short8v a0 = *reinterpret_cast<const short8v*>(kc + off);
                short8v a1 = *reinterpret_cast<const short8v*>(kc + off + 8192);
                if (ss & 1) {
                    s0b = __builtin_amdgcn_mfma_f32_16x16x32_bf16(a0, qf[ss], s0b, 0, 0, 0);
                    s1b = __builtin_amdgcn_mfma_f32_16x16x32_bf16(a1, qf[ss], s1b, 0, 0, 0);
                } else {
                    s0a = __builtin_amdgcn_mfma_f32_16x16x32_bf16(a0, qf[ss], s0a, 0, 0, 0);
                    s1a = __builtin_amdgcn_mfma_f32_16x16x32_bf16(a1, qf[ss], s1a, 0, 0, 0);
                }
            }
            __builtin_amdgcn_s_setprio(0);
            float4v s0, s1;
            #pragma unroll
            for (int r = 0; r < 4; ++r) { s0[r] = s0a[r] + s0b[r]; s1[r] = s1a[r] + s1b[r]; }

            // causal mask; lane holds kj = ks0 + sigma(g,e) for q = qrow
            float p[8];
            #pragma unroll
            for (int r = 0; r < 4; ++r) {
                int kj0 = ks0 + 4*g + r;
                p[r]     = (kj0      <= qrow) ? s0[r] : -3.0e38f;
                p[r + 4] = (kj0 + 16 <= qrow) ? s1[r] : -3.0e38f;
            }
            float mx = p[0];
            #pragma unroll
            for (int i2 = 1; i2 < 8; ++i2) mx = fmaxf(mx, p[i2]);

            // defer-max: row-max shuffles + rescale only when slack exceeded (or first tile)
            if (!__all(mx <= m_r + 8.f)) {
                float mrow = fmaxf(mx, __shfl_xor(mx, 16));
                mrow = fmaxf(mrow, __shfl_xor(mrow, 32));
                mrow = fmaxf(mrow, m_r);
                float corr = __expf(m_r - mrow);   // first tile: expf(-inf)=0
                m_r = mrow;
                l_par *= corr;
                #pragma unroll
                for (int dt = 0; dt < 32; ++dt) {
                    acc[dt][0] *= corr; acc[dt][1] *= corr;
                    acc[dt][2] *= corr; acc[dt][3] *= corr;
                }
            }
            // gated exp: fully-masked entries (incl. all-masked rows where m_r==-3e38) -> 0
            #pragma unroll
            for (int i2 = 0; i2 < 8; ++i2) {
                float e = __expf(p[i2] - m_r);
                p[i2] = (p[i2] > -1.0e37f) ? e : 0.f;
                l_par += p[i2];
            }

            // P fragment (lane-local): B-operand elems = P[q=lm][sigma(g,e)], values <= e^8
            short8v pf;
            #pragma unroll
            for (int i2 = 0; i2 < 8; ++i2) pf[i2] = f2bf(p[i2]);

            // PV (O^T): A = V^T rows (full 512 dims), literal offsets, B = pf
            __builtin_amdgcn_s_setprio(1);
            #pragma unroll
            for (int dt = 0; dt < 32; ++dt) {
                short8v vf = *reinterpret_cast<const short8v*>(vc + dt*512);
                acc[dt] = __builtin_amdgcn_mfma_f32_16x16x32_bf16(vf, pf, acc[dt], 0, 0, 0);
            }
            __builtin_amdgcn_s_setprio(0);
        }

        // phase epilogue: reduce l across the row's 4 g-lanes; store UNNORMALIZED U + (m,l)
        float l = l_par + __shfl_xor(l_par, 16);
        l += __shfl_xor(l, 32);
        const int orow = qbase + 16*qgp + lm;
        short* up = Uo + (size_t)(b*TT + orow)*D;
        #pragma unroll
        for (int dt = 0; dt < 32; ++dt) {
            short4v o = { f2bf(acc[dt][0]), f2bf(acc[dt][1]),
                          f2bf(acc[dt][2]), f2bf(acc[dt][3]) };
            *reinterpret_cast<short4v*>(up + 16*dt + 4*g) = o;
        }
        if (g == 0) {                          // one writer per row (lanes 0..15)
            mo[(size_t)b*TT + orow] = m_r;
            lo[(size_t)b*TT + orow] = l;
        }
    }
    #undef STAGE_KV
}

// ============ Merge the four key-quarters: O = sum_s U_s*w_s / sum_s l_s*w_s ============
__global__ __launch_bounds__(256) void merge_quads(
    const __hip_bfloat16* __restrict__ U0, const __hip_bfloat16* __restrict__ U1,
    const __hip_bfloat16* __restrict__ U2, const __hip_bfloat16* __restrict__ U3,
    const float* __restrict__ mArr, const float* __restrict__ lArr,
    __hip_bfloat16* __restrict__ ctx)
{
    const int BT = BB * TT;
    const int gidx = blockIdx.x * 256 + threadIdx.x;   // one thread per 8 cols
    const int row = gidx >> 6;
    const int c = (gidx & 63) * 8;
    float m0 = mArr[row], m1 = mArr[BT + row], m2 = mArr[2*BT + row], m3 = mArr[3*BT + row];
    float ms = fmaxf(fmaxf(m0, m1), fmaxf(m2, m3));
    float w0 = __expf(m0 - ms), w1 = __expf(m1 - ms);
    float w2 = __expf(m2 - ms), w3 = __expf(m3 - ms);
    float l = lArr[row]*w0 + lArr[BT + row]*w1 + lArr[2*BT + row]*w2 + lArr[3*BT + row]*w3;
    float inv = 1.f / l;
    w0 *= inv; w1 *= inv; w2 *= inv; w3 *= inv;
    size_t off = (size_t)row * D + c;
    short8v a = *reinterpret_cast<const short8v*>((const short*)U0 + off);
    short8v b = *reinterpret_cast<const short8v*>((const short*)U1 + off);
    short8v d = *reinterpret_cast<const short8v*>((const short*)U2 + off);
    short8v e = *reinterpret_cast<const short8v*>((const short*)U3 + off);
    short8v o;
    #pragma unroll
    for (int i = 0; i < 8; ++i)
        o[i] = f2bf(bf2f(a[i])*w0 + bf2f(b[i])*w1 + bf2f(d[i])*w2 + bf2f(e[i])*w3);
    *reinterpret_cast<short8v*>((short*)ctx + off) = o;
}

// ============ Output projection: d_out[t][e] = sum_d ctx[t][d] * Wo[e][d], f32 out ============
__global__ __launch_bounds__(256) void gemm_out(
    const __hip_bfloat16* __restrict__ Ab, const float* __restrict__ W,
    float* __restrict__ Cf)
{
    __shared__ short As[64][72];
    __shared__ short Bs[64][72];
    const int tid = threadIdx.x;
    const int m0 = blockIdx.x * 64, n0 = blockIdx.y * 64;
    const int w = tid >> 6, lane = tid & 63, lm = lane & 15, g = lane >> 4;
    const short* Ap = (const short*)Ab;

    float4v acc[4];
    #pragma unroll
    for (int i = 0; i < 4; ++i) acc[i] = (float4v){0.f,0.f,0.f,0.f};

    for (int k0 = 0; k0 < 512; k0 += 64) {
        __syncthreads();
        #pragma unroll
        for (int u = 0; u < 2; ++u) {          // stage A (bf16 ctx)
            int ch = tid + 256*u;
            int r = ch >> 3, c = (ch & 7) * 8;
            *reinterpret_cast<short8v*>(&As[r][c]) =
                *reinterpret_cast<const short8v*>(Ap + (size_t)(m0 + r)*512 + k0 + c);
        }
        #pragma unroll
        for (int u = 0; u < 4; ++u) {          // stage B (Wo f32 -> bf16)
            int ch = tid + 256*u;
            int r = ch >> 4, c = (ch & 15) * 4;
            float4 wv = *reinterpret_cast<const float4*>(W + (size_t)(n0 + r)*512 + k0 + c);
            short4v sv = { f2bf(wv.x), f2bf(wv.y), f2bf(wv.z), f2bf(wv.w) };
            *reinterpret_cast<short4v*>(&Bs[r][c]) = sv;
        }
        __syncthreads();
        #pragma unroll
        for (int ks = 0; ks < 2; ++ks) {
            short8v a = *reinterpret_cast<const short8v*>(&As[16*w + lm][ks*32 + 8*g]);
            #pragma unroll
            for (int nt = 0; nt < 4; ++nt) {
                short8v bv = *reinterpret_cast<const short8v*>(&Bs[16*nt + lm][ks*32 + 8*g]);
                acc[nt] = __builtin_amdgcn_mfma_f32_16x16x32_bf16(a, bv, acc[nt], 0, 0, 0);
            }
        }
    }
    #pragma unroll
    for (int nt = 0; nt < 4; ++nt)
        #pragma unroll
        for (int r = 0; r < 4; ++r) {
            int row = m0 + 16*w + 4*g + r;
            int col = n0 + 16*nt + lm;
            Cf[(size_t)row*512 + col] = acc[nt][r];
        }
}

extern "C" void kernel_launch(void* const* d_in, const int* in_sizes, int n_in,
                              void* d_out, int out_size, void* d_ws, size_t ws_size,
                              hipStream_t stream) {
    const float* x  = (const float*)d_in[0];
    const float* Wq = (const float*)d_in[1];
    const float* Wk = (const float*)d_in[2];
    const float* Wv = (const float*)d_in[3];
    const float* Wo = (const float*)d_in[4];
    float* out = (float*)d_out;

    const size_t n = (size_t)BB * TT * D;                 // 8.4M elems
    __hip_bfloat16* qb_  = (__hip_bfloat16*)d_ws;
    __hip_bfloat16* kb_  = qb_ + n;
    __hip_bfloat16* vt_  = kb_ + n;                       // sigma-permuted V^T (written by gemm_qkv)
    __hip_bfloat16* ctxb = vt_ + n;
    __hip_bfloat16* U1   = ctxb + n;                      // 3 x 16.8MB bf16
    __hip_bfloat16* U2   = U1 + n;
    __hip_bfloat16* U3   = U2 + n;
    float* mArr = (float*)(U3 + n);                       // 4 x BT f32 = 1MB
    float* lArr = mArr + (size_t)4 * BB * TT;             // 4 x BT f32 = 1MB
    __hip_bfloat16* U0 = (__hip_bfloat16*)out;            // d_out as scratch (overwritten later)

    gemm_qkv<<<dim3(256, 8), 256, 0, stream>>>(x, Wq, Wk, Wv, qb_, kb_, vt_);
    attn_split<<<dim3(64 * BB), 512, 0, stream>>>(qb_, kb_, vt_, U0, U1, U2, U3, mArr, lArr);
    merge_quads<<<dim3(BB * TT / 4), 256, 0, stream>>>(U0, U1, U2, U3, mArr, lArr, ctxb);
    gemm_out<<<dim3(256, 8, 1), 256, 0, stream>>>(ctxb, Wo, out);
}